// Round 30
// baseline (229.410 us; speedup 1.0000x reference)
//
#include <hip/hip_runtime.h>
#include <hip/hip_bf16.h>
#include <cstdint>

typedef unsigned short u16;
typedef __attribute__((ext_vector_type(4))) float f32x4;
typedef __attribute__((ext_vector_type(8))) short s16x8;
typedef __attribute__((ext_vector_type(4))) unsigned int u32x4;
typedef __attribute__((ext_vector_type(2))) unsigned int u32x2;
typedef __attribute__((ext_vector_type(4))) unsigned short u16x4;
typedef __attribute__((ext_vector_type(8))) unsigned short u16x8;

#define MFMA16(a, b, c) __builtin_amdgcn_mfma_f32_16x16x32_bf16(a, b, c, 0, 0, 0)
#define GLOAD16(g, l) __builtin_amdgcn_global_load_lds((const __attribute__((address_space(1))) void*)(g), (__attribute__((address_space(3))) void*)(l), 16, 0, 0)

__device__ __forceinline__ u16 f2bf(float f) {
    union { float f; uint32_t u; } v{f};
    uint32_t r = v.u + 0x7FFF + ((v.u >> 16) & 1);
    return (u16)(r >> 16);
}
__device__ __forceinline__ float bf2f(u16 b) {
    union { uint32_t u; float f; } v;
    v.u = ((uint32_t)b) << 16;
    return v.f;
}

// ---------------- fused cast (all 5 inputs) + RoPE table, 1 launch ----------------
__global__ void cast_all(const float* __restrict__ h, const float* __restrict__ wq,
                         const float* __restrict__ wk, const float* __restrict__ wv,
                         const float* __restrict__ wo, const int* __restrict__ pos,
                         u16* __restrict__ Xb, u16* __restrict__ WB, u16* __restrict__ WoB,
                         float* __restrict__ ct, float* __restrict__ st) {
    if (blockIdx.x >= 18432) {
        int i = (blockIdx.x - 18432) * 256 + threadIdx.x;   // 1024*256 = 262144
        int j = i & 63;
        int bs = i >> 6;
        float p = (float)pos[bs];
        float invf = powf(10000.0f, -(float)j * (1.0f / 64.0f));
        float ang = p * invf;
        ct[i] = cosf(ang);
        st[i] = sinf(ang);
        return;
    }
    int i = blockIdx.x * 256 + threadIdx.x;   // 18432*256 = 4718592 exactly
    const float* src; u16* dst; int off;
    if (i < 2097152)      { src = h;  dst = Xb;           off = i; }
    else if (i < 3145728) { src = wq; dst = WB;           off = i - 2097152; }
    else if (i < 3407872) { src = wk; dst = WB + 4194304; off = i - 3145728; }
    else if (i < 3670016) { src = wv; dst = WB + 5242880; off = i - 3407872; }
    else                  { src = wo; dst = WoB;          off = i - 3670016; }
    float4 f = ((const float4*)src)[off];
    u16x4 o = { f2bf(f.x), f2bf(f.y), f2bf(f.z), f2bf(f.w) };
    ((u16x4*)dst)[off] = o;
}

// ---------------- GEMM C = A @ B^T, 2-phase double-buffered + XCD swizzle ----------------
template <int FUSE>
__global__ __launch_bounds__(256) void gemm_bt(const u16* __restrict__ A, const u16* __restrict__ Bw,
                                               float* __restrict__ C, int M, int N, int K,
                                               const float* __restrict__ ct, const float* __restrict__ st,
                                               u16* __restrict__ Qb, u16* __restrict__ Kb,
                                               u16* __restrict__ Vb) {
    __shared__ u16 Sh[32768];                // 64KB: buf bi at Sh + bi*16384 {A:0-8K, B:8K-16K}
    const int tid = threadIdx.x;
    const int lane = tid & 63, wid = tid >> 6;
    const int g = lane >> 4, r = lane & 15;

    const int gx = gridDim.x, nwg = gx * gridDim.y;
    int lid = blockIdx.y * gx + blockIdx.x;
    int swz = (lid % 8) * (nwg / 8) + lid / 8;
    const int bxi = swz % gx, byi = swz / gx;

    const size_t bm = (size_t)byi * 128, bn = (size_t)bxi * 128;
    const int wr = (wid >> 1) * 64, wc = (wid & 1) * 64;

    const int srow = wid * 32 + (lane >> 3);
    const int schunk = (lane & 7) ^ ((lane >> 3) & 7);
    const u16* aSrc = A + (bm + srow) * (size_t)K + schunk * 8;
    const u16* bSrc = Bw + (bn + srow) * (size_t)K + schunk * 8;

    auto STAGE = [&](int ktEl, int bi) {
        u16* aD = Sh + bi * 16384 + wid * 2048;
        u16* bD = Sh + bi * 16384 + 8192 + wid * 2048;
#pragma unroll
        for (int j = 0; j < 4; ++j) {
            GLOAD16(aSrc + (size_t)(j * 8) * K + ktEl, aD + j * 512);
            GLOAD16(bSrc + (size_t)(j * 8) * K + ktEl, bD + j * 512);
        }
    };

    f32x4 acc[4][4] = {};
    const int nk = K >> 6;
    STAGE(0, 0);
    __syncthreads();
    for (int t = 0; t < nk; ++t) {
        if (t + 1 < nk) STAGE((t + 1) << 6, (t + 1) & 1);
        const u16* As = Sh + (t & 1) * 16384;
        const u16* Bs = As + 8192;
        s16x8 af[4][2], bfr[4][2];
#pragma unroll
        for (int m = 0; m < 4; ++m)
#pragma unroll
            for (int kk = 0; kk < 2; ++kk) {
                int rowa = wr + m * 16 + r;
                af[m][kk] = *(const s16x8*)(As + rowa * 64 + (((kk * 4 + g) ^ (rowa & 7)) << 3));
                int rowb = wc + m * 16 + r;
                bfr[m][kk] = *(const s16x8*)(Bs + rowb * 64 + (((kk * 4 + g) ^ (rowb & 7)) << 3));
            }
#pragma unroll
        for (int m = 0; m < 4; ++m)
#pragma unroll
            for (int n = 0; n < 4; ++n) {
                acc[m][n] = MFMA16(af[m][0], bfr[n][0], acc[m][n]);
                acc[m][n] = MFMA16(af[m][1], bfr[n][1], acc[m][n]);
            }
        __syncthreads();
    }
    if (FUSE == 0) {
#pragma unroll
        for (int m = 0; m < 4; ++m)
#pragma unroll
            for (int n = 0; n < 4; ++n)
#pragma unroll
                for (int i = 0; i < 4; ++i) {
                    size_t row = bm + wr + m * 16 + g * 4 + i;
                    size_t col = bn + wc + n * 16 + r;
                    C[row * N + col] = acc[m][n][i];
                }
        return;
    }
    const int hb = bxi;
    if (hb < 20) {
#pragma unroll
        for (int m = 0; m < 4; ++m)
#pragma unroll
            for (int n = 0; n < 4; ++n)
#pragma unroll
                for (int i = 0; i < 4; ++i) {
                    int rowl = wr + m * 16 + g * 4 + i;
                    int col = wc + n * 16 + r;
                    int c4 = col >> 3;
                    *(u16*)((char*)Sh + rowl * 256 + (((c4 ^ (rowl & 15))) << 4) + ((col & 7) << 1)) =
                        f2bf(acc[m][n][i]);
                }
        __syncthreads();
        if (tid < 128) {
            const int rowl = tid;
            const size_t tok = bm + rowl;
            const int b = (int)(tok >> 11), s = (int)(tok & 2047);
            u16* dst;
            if (hb < 16) dst = Qb + (((size_t)(b * 16 + hb) * 2048 + s) << 7);
            else         dst = Kb + (((size_t)(b * 4 + (hb - 16)) * 2048 + s) << 7);
            const char* tb = (const char*)Sh + rowl * 256;
            const float* ctr = ct + tok * 64;
            const float* str = st + tok * 64;
#pragma unroll
            for (int c4 = 0; c4 < 8; ++c4) {
                u32x4 lo4 = *(const u32x4*)(tb + ((c4 ^ (rowl & 15)) << 4));
                u32x4 hi4 = *(const u32x4*)(tb + (((c4 + 8) ^ (rowl & 15)) << 4));
                const u16* lo = (const u16*)&lo4;
                const u16* hi = (const u16*)&hi4;
                u16x4 o0, o1, o2, o3;
                u16* olo[2] = { (u16*)&o0, (u16*)&o1 };
                u16* ohi[2] = { (u16*)&o2, (u16*)&o3 };
#pragma unroll
                for (int j = 0; j < 8; ++j) {
                    float c = ctr[c4 * 8 + j], sn = str[c4 * 8 + j];
                    float xl = bf2f(lo[j]), xh = bf2f(hi[j]);
                    olo[j >> 2][j & 3] = f2bf(xl * c - xh * sn);
                    ohi[j >> 2][j & 3] = f2bf(xh * c + xl * sn);
                }
                *(u16x4*)(dst + c4 * 8) = o0;
                *(u16x4*)(dst + c4 * 8 + 4) = o1;
                *(u16x4*)(dst + 64 + c4 * 8) = o2;
                *(u16x4*)(dst + 64 + c4 * 8 + 4) = o3;
            }
        }
    } else {
#pragma unroll
        for (int m = 0; m < 4; ++m) {
            int tokb = wr + m * 16 + g * 4;
            int chunk = tokb >> 3;
            int sub = (g & 1) * 8;
#pragma unroll
            for (int n = 0; n < 4; ++n) {
                int d = wc + n * 16 + r;
                u16x4 v = { f2bf(acc[m][n][0]), f2bf(acc[m][n][1]),
                            f2bf(acc[m][n][2]), f2bf(acc[m][n][3]) };
                *(u16x4*)((char*)Sh + d * 256 + (((chunk ^ (d & 15))) << 4) + sub) = v;
            }
        }
        __syncthreads();
        const int b = (int)(bm >> 11), s0 = (int)(bm & 2047);
        u16* dst = Vb + (size_t)(b * 4 + (hb - 20)) * 262144;
        const int dd = tid >> 1, half = (tid & 1) * 8;
#pragma unroll
        for (int c8 = 0; c8 < 8; ++c8) {
            int sc = half + c8;
            u32x4 v4 = *(const u32x4*)((const char*)Sh + dd * 256 + (((sc ^ (dd & 15))) << 4));
            *(u32x4*)(dst + (size_t)dd * 2048 + s0 + sc * 8) = v4;
        }
    }
}

// ---------------- causal flash attention (round-25/27: K dbuf, write-after-drain) ----------------
__global__ __launch_bounds__(256, 2) void attn_k(const u16* __restrict__ Qb, const u16* __restrict__ Kb,
                                                 const u16* __restrict__ Vb, u16* __restrict__ Ob) {
    __shared__ char smem[65536];
    u16* Vts = (u16*)(smem + 32768);    // 16KB [128 d][64 kv], chunk^=(d&7)^((d>>3)&7)
    char* Pall = smem + 49152;          // 16KB: 8 x 2KB per (wave,frag)
    const int tid = threadIdx.x;
    const int lane = tid & 63, w = tid >> 6;
    const int g = lane >> 4, r = lane & 15;

    // balanced complementary remap (bijective over 512)
    const int lid = blockIdx.y * gridDim.x + blockIdx.x;  // 0..511
    const int cpy = lid >> 8, p = lid & 255;
    const int bh = p & 31;
    const int qblk = cpy ? (7 - (p >> 5)) : ((p >> 5) + 8);

    const int b = bh >> 4, h = bh & 15;
    const int hkv = h >> 2;
    const int q0 = qblk * 128;
    const u16* Qh = Qb + ((size_t)(b * 16 + h) << 18);
    const u16* Kh = Kb + ((size_t)(b * 4 + hkv) << 18);
    const u16* Vh = Vb + ((size_t)(b * 4 + hkv) << 18);   // Vt: [128 d][2048 s]

    s16x8 qf[2][4];
#pragma unroll
    for (int qq = 0; qq < 2; ++qq)
#pragma unroll
        for (int c = 0; c < 4; ++c)
            qf[qq][c] = *(const s16x8*)(Qh + (size_t)(q0 + qq * 64 + w * 16 + r) * 128 + c * 32 + g * 8);

    f32x4 o[2][8] = {};
    float mrun[2] = {-1e30f, -1e30f};
    float lrun[2] = {0.f, 0.f};
    const int fmax[2] = { q0 + w * 16 + 15, q0 + 64 + w * 16 + 15 };

    const int ntiles = 2 * qblk + 2;
    const int krow0 = tid >> 4, kch = tid & 15;

    u32x4 kpr[4], vpr[4];
    // ---- prologue: stage K0/V0, preload K1/V1 ----
#pragma unroll
    for (int it = 0; it < 4; ++it)
        kpr[it] = *(const u32x4*)(Kh + (size_t)(krow0 + it * 16) * 128 + kch * 8);
#pragma unroll
    for (int it = 0; it < 4; ++it) {
        int task = tid + it * 256;
        vpr[it] = *(const u32x4*)(Vh + (size_t)(task >> 3) * 2048 + (task & 7) * 8);
    }
#pragma unroll
    for (int it = 0; it < 4; ++it) {
        int row = krow0 + it * 16;
        *(u32x4*)(smem + row * 256 + ((kch ^ (row & 7)) << 4)) = kpr[it];   // buf0
    }
#pragma unroll
    for (int it = 0; it < 4; ++it) {
        int task = tid + it * 256;
        int d = task >> 3, ch = task & 7;
        *(u32x4*)((char*)Vts + d * 128 + ((ch ^ (d & 7) ^ ((d >> 3) & 7)) << 4)) = vpr[it];
    }
    if (ntiles > 1) {
#pragma unroll
        for (int it = 0; it < 4; ++it)
            kpr[it] = *(const u32x4*)(Kh + (size_t)(64 + krow0 + it * 16) * 128 + kch * 8);
#pragma unroll
        for (int it = 0; it < 4; ++it) {
            int task = tid + it * 256;
            vpr[it] = *(const u32x4*)(Vh + (size_t)(task >> 3) * 2048 + 64 + (task & 7) * 8);
        }
    }
    __syncthreads();

    for (int t = 0; t < ntiles; ++t) {
        const int kv0 = t * 64;
        const char* kb = smem + ((t & 1) << 14);
        // ---- QK^T from K[t] ----
        f32x4 st4[2][4];
#pragma unroll
        for (int ts = 0; ts < 4; ++ts) {
            int row = ts * 16 + r;
            s16x8 kf[4];
#pragma unroll
            for (int c = 0; c < 4; ++c)
                kf[c] = *(const s16x8*)(kb + row * 256 + (((c * 4 + g) ^ (row & 7)) << 4));
            f32x4 a0 = {}, a1 = {};
            if (kv0 <= fmax[0])
#pragma unroll
                for (int c = 0; c < 4; ++c) a0 = MFMA16(kf[c], qf[0][c], a0);
            if (kv0 <= fmax[1])
#pragma unroll
                for (int c = 0; c < 4; ++c) a1 = MFMA16(kf[c], qf[1][c], a1);
            st4[0][ts] = a0;
            st4[1][ts] = a1;
        }
        // ---- per-frag online softmax (defer-max THR=8) + P write ----
#pragma unroll
        for (int qq = 0; qq < 2; ++qq) {
            if (kv0 > fmax[qq]) continue;   // wave-uniform
            const int qg = q0 + qq * 64 + w * 16 + r;
            float sv[16];
            float mtile = -1e30f;
#pragma unroll
            for (int ts = 0; ts < 4; ++ts)
#pragma unroll
                for (int i = 0; i < 4; ++i) {
                    int kvg = kv0 + ts * 16 + g * 4 + i;
                    float s = st4[qq][ts][i] * 0.08838834764831845f;
                    s = (kvg > qg) ? -1e30f : s;
                    sv[ts * 4 + i] = s;
                    mtile = fmaxf(mtile, s);
                }
            mtile = fmaxf(mtile, __shfl_xor(mtile, 16));
            mtile = fmaxf(mtile, __shfl_xor(mtile, 32));
            float mold = mrun[qq];
            if (!__all(mtile <= mold + 8.0f)) {
                float mnew = fmaxf(mold, mtile);
                float corr = __expf(mold - mnew);
#pragma unroll
                for (int dsb = 0; dsb < 8; ++dsb)
#pragma unroll
                    for (int i = 0; i < 4; ++i) o[qq][dsb][i] *= corr;
                lrun[qq] *= corr;
                mrun[qq] = mnew;
            }
            float mm = mrun[qq];
            float psum = 0.f;
            unsigned int pw[8];
#pragma unroll
            for (int ts = 0; ts < 4; ++ts) {
                float p0 = __expf(sv[ts * 4 + 0] - mm);
                float p1 = __expf(sv[ts * 4 + 1] - mm);
                float p2 = __expf(sv[ts * 4 + 2] - mm);
                float p3 = __expf(sv[ts * 4 + 3] - mm);
                psum += (p0 + p1) + (p2 + p3);
                pw[ts * 2 + 0] = (unsigned int)f2bf(p0) | ((unsigned int)f2bf(p1) << 16);
                pw[ts * 2 + 1] = (unsigned int)f2bf(p2) | ((unsigned int)f2bf(p3) << 16);
            }
            psum += __shfl_xor(psum, 16);
            psum += __shfl_xor(psum, 32);
            lrun[qq] += psum;
            char* pbase = Pall + (w * 2 + qq) * 2048;
#pragma unroll
            for (int ts = 0; ts < 4; ++ts) {
                int chunk = (ts * 2 + (g >> 1)) ^ (r & 7);
                u32x2 val = { pw[ts * 2], pw[ts * 2 + 1] };
                *(u32x2*)(pbase + r * 128 + chunk * 16 + (g & 1) * 8) = val;
            }
        }
        asm volatile("s_waitcnt lgkmcnt(0)" ::: "memory");
        // ---- write K[t+1] to inactive buffer AFTER the drain (overlaps PV); issue K[t+2] ----
        if (t + 1 < ntiles) {
            char* kbn = smem + (((t + 1) & 1) << 14);
#pragma unroll
            for (int it = 0; it < 4; ++it) {
                int row = krow0 + it * 16;
                *(u32x4*)(kbn + row * 256 + ((kch ^ (row & 7)) << 4)) = kpr[it];
            }
            if (t + 2 < ntiles) {
                const int kn2 = kv0 + 128;
#pragma unroll
                for (int it = 0; it < 4; ++it)
                    kpr[it] = *(const u32x4*)(Kh + (size_t)(kn2 + krow0 + it * 16) * 128 + kch * 8);
            }
        }
        // ---- PV from Vts ----
#pragma unroll
        for (int c = 0; c < 2; ++c) {
            s16x8 vf[8];
#pragma unroll
            for (int dsb = 0; dsb < 8; ++dsb) {
                int d = dsb * 16 + r;
                vf[dsb] = *(const s16x8*)((const char*)Vts + d * 128 +
                    ((((c * 4 + g) ^ (d & 7) ^ ((d >> 3) & 7))) << 4));
            }
#pragma unroll
            for (int qq = 0; qq < 2; ++qq) {
                if (kv0 > fmax[qq]) continue;
                s16x8 pf = *(const s16x8*)(Pall + (w * 2 + qq) * 2048 + r * 128 +
                                           (((c * 4 + g) ^ (r & 7)) << 4));
#pragma unroll
                for (int dsb = 0; dsb < 8; ++dsb)
                    o[qq][dsb] = MFMA16(vf[dsb], pf, o[qq][dsb]);
            }
        }
        __syncthreads();                    // all waves done with V[t]; K[t+1] writes flushed
        // ---- write V[t+1]; issue V[t+2] ----
        if (t + 1 < ntiles) {
#pragma unroll
            for (int it = 0; it < 4; ++it) {
                int task = tid + it * 256;
                int d = task >> 3, ch = task & 7;
                *(u32x4*)((char*)Vts + d * 128 + ((ch ^ (d & 7) ^ ((d >> 3) & 7)) << 4)) = vpr[it];
            }
            if (t + 2 < ntiles) {
                const int kn2 = kv0 + 128;
#pragma unroll
                for (int it = 0; it < 4; ++it) {
                    int task = tid + it * 256;
                    vpr[it] = *(const u32x4*)(Vh + (size_t)(task >> 3) * 2048 + kn2 + (task & 7) * 8);
                }
            }
        }
        __syncthreads();                    // V[t+1] (and K[t+1]) visible for next step
    }
    // ---- epilogue: normalize, per-(wave,frag) LDS transpose, coalesced store ----
#pragma unroll
    for (int qq = 0; qq < 2; ++qq) {
        float linv = 1.0f / lrun[qq];
        char* obase = smem + (w << 13) + (qq << 12);   // 4KB: [16 q][128 d] bf16 (K bufs dead)
#pragma unroll
        for (int dsb = 0; dsb < 8; ++dsb)
#pragma unroll
            for (int i = 0; i < 4; ++i) {
                int d = dsb * 16 + g * 4 + i;
                *(u16*)(obase + r * 256 + d * 2) = f2bf(o[qq][dsb][i] * linv);
            }
    }
    asm volatile("s_waitcnt lgkmcnt(0)" ::: "memory");
    const int rr = lane >> 2, cbo = (lane & 3) * 32;
#pragma unroll
    for (int qq = 0; qq < 2; ++qq) {
        char* obase = smem + (w << 13) + (qq << 12);
        size_t oidx = ((size_t)b * 2048 + q0 + qq * 64 + w * 16 + rr) * 2048 + h * 128 + cbo;
#pragma unroll
        for (int p2 = 0; p2 < 4; ++p2) {
            u32x4 vv = *(const u32x4*)(obase + rr * 256 + cbo * 2 + p2 * 16);
            *(u32x4*)(Ob + oidx + p2 * 8) = vv;
        }
    }
}

extern "C" void kernel_launch(void* const* d_in, const int* in_sizes, int n_in,
                              void* d_out, int out_size, void* d_ws, size_t ws_size,
                              hipStream_t stream) {
    const float* hidden = (const float*)d_in[0];
    const int* pos = (const int*)d_in[1];
    const float* wq = (const float*)d_in[2];
    const float* wk = (const float*)d_in[3];
    const float* wv = (const float*)d_in[4];
    const float* wo = (const float*)d_in[5];
    float* out = (float*)d_out;

    char* ws = (char*)d_ws;
    size_t off = 0;
    auto alloc = [&](size_t bytes) { char* p = ws + off; off += (bytes + 255) & ~255ULL; return p; };
    u16* Xb   = (u16*)alloc(8388608ULL * 2);     // hidden bf16 [4096][2048]
    u16* WB   = (u16*)alloc(6291456ULL * 2);     // [wq;wk;wv] bf16 [3072][2048]
    u16* WoB  = (u16*)alloc(4194304ULL * 2);     // wo bf16 [2048][2048]
    u16* Qb   = (u16*)alloc(8388608ULL * 2);     // [B*16][2048][128]
    u16* Kb   = (u16*)alloc(2097152ULL * 2);     // [B*4][2048][128]
    u16* Vb   = (u16*)alloc(2097152ULL * 2);     // [B*4][128][2048] (transposed)
    u16* Ab   = (u16*)alloc(8388608ULL * 2);     // attn out bf16 [4096][2048]
    float* ctab = (float*)alloc(262144ULL * 4);
    float* stab = (float*)alloc(262144ULL * 4);

    cast_all<<<19456, 256, 0, stream>>>(hidden, wq, wk, wv, wo, pos, Xb, WB, WoB, ctab, stab);
    gemm_bt<1><<<dim3(24, 32), 256, 0, stream>>>(Xb, WB, nullptr, 4096, 3072, 2048,
                                                 ctab, stab, Qb, Kb, Vb);
    attn_k<<<dim3(16, 32), 256, 0, stream>>>(Qb, Kb, Vb, Ab);
    gemm_bt<0><<<dim3(16, 32), 256, 0, stream>>>(Ab, WoB, out, 4096, 2048, 2048,
                                                 nullptr, nullptr, nullptr, nullptr, nullptr);
}

// Round 31
// 228.756 us; speedup vs baseline: 1.0029x; 1.0029x over previous
//
#include <hip/hip_runtime.h>
#include <hip/hip_bf16.h>
#include <cstdint>

typedef unsigned short u16;
typedef __attribute__((ext_vector_type(4))) float f32x4;
typedef __attribute__((ext_vector_type(8))) short s16x8;
typedef __attribute__((ext_vector_type(4))) unsigned int u32x4;
typedef __attribute__((ext_vector_type(2))) unsigned int u32x2;
typedef __attribute__((ext_vector_type(4))) unsigned short u16x4;
typedef __attribute__((ext_vector_type(8))) unsigned short u16x8;

#define MFMA16(a, b, c) __builtin_amdgcn_mfma_f32_16x16x32_bf16(a, b, c, 0, 0, 0)
#define GLOAD16(g, l) __builtin_amdgcn_global_load_lds((const __attribute__((address_space(1))) void*)(g), (__attribute__((address_space(3))) void*)(l), 16, 0, 0)

__device__ __forceinline__ u16 f2bf(float f) {
    union { float f; uint32_t u; } v{f};
    uint32_t r = v.u + 0x7FFF + ((v.u >> 16) & 1);
    return (u16)(r >> 16);
}
__device__ __forceinline__ float bf2f(u16 b) {
    union { uint32_t u; float f; } v;
    v.u = ((uint32_t)b) << 16;
    return v.f;
}

// ---------------- fused cast (all 5 inputs) + RoPE table, 1 launch ----------------
__global__ void cast_all(const float* __restrict__ h, const float* __restrict__ wq,
                         const float* __restrict__ wk, const float* __restrict__ wv,
                         const float* __restrict__ wo, const int* __restrict__ pos,
                         u16* __restrict__ Xb, u16* __restrict__ WB, u16* __restrict__ WoB,
                         float* __restrict__ ct, float* __restrict__ st) {
    if (blockIdx.x >= 18432) {
        int i = (blockIdx.x - 18432) * 256 + threadIdx.x;   // 1024*256 = 262144
        int j = i & 63;
        int bs = i >> 6;
        float p = (float)pos[bs];
        float invf = powf(10000.0f, -(float)j * (1.0f / 64.0f));
        float ang = p * invf;
        ct[i] = cosf(ang);
        st[i] = sinf(ang);
        return;
    }
    int i = blockIdx.x * 256 + threadIdx.x;   // 18432*256 = 4718592 exactly
    const float* src; u16* dst; int off;
    if (i < 2097152)      { src = h;  dst = Xb;           off = i; }
    else if (i < 3145728) { src = wq; dst = WB;           off = i - 2097152; }
    else if (i < 3407872) { src = wk; dst = WB + 4194304; off = i - 3145728; }
    else if (i < 3670016) { src = wv; dst = WB + 5242880; off = i - 3407872; }
    else                  { src = wo; dst = WoB;          off = i - 3670016; }
    float4 f = ((const float4*)src)[off];
    u16x4 o = { f2bf(f.x), f2bf(f.y), f2bf(f.z), f2bf(f.w) };
    ((u16x4*)dst)[off] = o;
}

// ---------------- GEMM C = A @ B^T, 2-phase double-buffered + XCD swizzle ----------------
// FUSE=0: plain f32 C store (O-proj). FUSE=1: QKV path — RoPE+scatter epilogue
// (all 256 threads: 2 threads/token-row, 4 chunk-pairs each); V stored transposed.
template <int FUSE>
__global__ __launch_bounds__(256) void gemm_bt(const u16* __restrict__ A, const u16* __restrict__ Bw,
                                               float* __restrict__ C, int M, int N, int K,
                                               const float* __restrict__ ct, const float* __restrict__ st,
                                               u16* __restrict__ Qb, u16* __restrict__ Kb,
                                               u16* __restrict__ Vb) {
    __shared__ u16 Sh[32768];                // 64KB: buf bi at Sh + bi*16384 {A:0-8K, B:8K-16K}
    const int tid = threadIdx.x;
    const int lane = tid & 63, wid = tid >> 6;
    const int g = lane >> 4, r = lane & 15;

    const int gx = gridDim.x, nwg = gx * gridDim.y;
    int lid = blockIdx.y * gx + blockIdx.x;
    int swz = (lid % 8) * (nwg / 8) + lid / 8;
    const int bxi = swz % gx, byi = swz / gx;

    const size_t bm = (size_t)byi * 128, bn = (size_t)bxi * 128;
    const int wr = (wid >> 1) * 64, wc = (wid & 1) * 64;

    const int srow = wid * 32 + (lane >> 3);
    const int schunk = (lane & 7) ^ ((lane >> 3) & 7);
    const u16* aSrc = A + (bm + srow) * (size_t)K + schunk * 8;
    const u16* bSrc = Bw + (bn + srow) * (size_t)K + schunk * 8;

    auto STAGE = [&](int ktEl, int bi) {
        u16* aD = Sh + bi * 16384 + wid * 2048;
        u16* bD = Sh + bi * 16384 + 8192 + wid * 2048;
#pragma unroll
        for (int j = 0; j < 4; ++j) {
            GLOAD16(aSrc + (size_t)(j * 8) * K + ktEl, aD + j * 512);
            GLOAD16(bSrc + (size_t)(j * 8) * K + ktEl, bD + j * 512);
        }
    };

    f32x4 acc[4][4] = {};
    const int nk = K >> 6;
    STAGE(0, 0);
    __syncthreads();
    for (int t = 0; t < nk; ++t) {
        if (t + 1 < nk) STAGE((t + 1) << 6, (t + 1) & 1);
        const u16* As = Sh + (t & 1) * 16384;
        const u16* Bs = As + 8192;
        s16x8 af[4][2], bfr[4][2];
#pragma unroll
        for (int m = 0; m < 4; ++m)
#pragma unroll
            for (int kk = 0; kk < 2; ++kk) {
                int rowa = wr + m * 16 + r;
                af[m][kk] = *(const s16x8*)(As + rowa * 64 + (((kk * 4 + g) ^ (rowa & 7)) << 3));
                int rowb = wc + m * 16 + r;
                bfr[m][kk] = *(const s16x8*)(Bs + rowb * 64 + (((kk * 4 + g) ^ (rowb & 7)) << 3));
            }
#pragma unroll
        for (int m = 0; m < 4; ++m)
#pragma unroll
            for (int n = 0; n < 4; ++n) {
                acc[m][n] = MFMA16(af[m][0], bfr[n][0], acc[m][n]);
                acc[m][n] = MFMA16(af[m][1], bfr[n][1], acc[m][n]);
            }
        __syncthreads();
    }
    if (FUSE == 0) {
#pragma unroll
        for (int m = 0; m < 4; ++m)
#pragma unroll
            for (int n = 0; n < 4; ++n)
#pragma unroll
                for (int i = 0; i < 4; ++i) {
                    size_t row = bm + wr + m * 16 + g * 4 + i;
                    size_t col = bn + wc + n * 16 + r;
                    C[row * N + col] = acc[m][n][i];
                }
        return;
    }
    const int hb = bxi;
    if (hb < 20) {
#pragma unroll
        for (int m = 0; m < 4; ++m)
#pragma unroll
            for (int n = 0; n < 4; ++n)
#pragma unroll
                for (int i = 0; i < 4; ++i) {
                    int rowl = wr + m * 16 + g * 4 + i;
                    int col = wc + n * 16 + r;
                    int c4 = col >> 3;
                    *(u16*)((char*)Sh + rowl * 256 + (((c4 ^ (rowl & 15))) << 4) + ((col & 7) << 1)) =
                        f2bf(acc[m][n][i]);
                }
        __syncthreads();
        {
            // all 256 threads: 2 threads per token-row, 4 chunk-pairs each
            const int rowl = tid >> 1;
            const int c4b = (tid & 1) * 4;
            const size_t tok = bm + rowl;
            const int b = (int)(tok >> 11), s = (int)(tok & 2047);
            u16* dst;
            if (hb < 16) dst = Qb + (((size_t)(b * 16 + hb) * 2048 + s) << 7);
            else         dst = Kb + (((size_t)(b * 4 + (hb - 16)) * 2048 + s) << 7);
            const char* tb = (const char*)Sh + rowl * 256;
            const float* ctr = ct + tok * 64;
            const float* str = st + tok * 64;
#pragma unroll
            for (int c4i = 0; c4i < 4; ++c4i) {
                int c4 = c4b + c4i;
                u32x4 lo4 = *(const u32x4*)(tb + ((c4 ^ (rowl & 15)) << 4));
                u32x4 hi4 = *(const u32x4*)(tb + (((c4 + 8) ^ (rowl & 15)) << 4));
                const u16* lo = (const u16*)&lo4;
                const u16* hi = (const u16*)&hi4;
                u16x4 o0, o1, o2, o3;
                u16* olo[2] = { (u16*)&o0, (u16*)&o1 };
                u16* ohi[2] = { (u16*)&o2, (u16*)&o3 };
#pragma unroll
                for (int j = 0; j < 8; ++j) {
                    float c = ctr[c4 * 8 + j], sn = str[c4 * 8 + j];
                    float xl = bf2f(lo[j]), xh = bf2f(hi[j]);
                    olo[j >> 2][j & 3] = f2bf(xl * c - xh * sn);
                    ohi[j >> 2][j & 3] = f2bf(xh * c + xl * sn);
                }
                *(u16x4*)(dst + c4 * 8) = o0;
                *(u16x4*)(dst + c4 * 8 + 4) = o1;
                *(u16x4*)(dst + 64 + c4 * 8) = o2;
                *(u16x4*)(dst + 64 + c4 * 8 + 4) = o3;
            }
        }
    } else {
#pragma unroll
        for (int m = 0; m < 4; ++m) {
            int tokb = wr + m * 16 + g * 4;
            int chunk = tokb >> 3;
            int sub = (g & 1) * 8;
#pragma unroll
            for (int n = 0; n < 4; ++n) {
                int d = wc + n * 16 + r;
                u16x4 v = { f2bf(acc[m][n][0]), f2bf(acc[m][n][1]),
                            f2bf(acc[m][n][2]), f2bf(acc[m][n][3]) };
                *(u16x4*)((char*)Sh + d * 256 + (((chunk ^ (d & 15))) << 4) + sub) = v;
            }
        }
        __syncthreads();
        const int b = (int)(bm >> 11), s0 = (int)(bm & 2047);
        u16* dst = Vb + (size_t)(b * 4 + (hb - 20)) * 262144;
        const int dd = tid >> 1, half = (tid & 1) * 8;
#pragma unroll
        for (int c8 = 0; c8 < 8; ++c8) {
            int sc = half + c8;
            u32x4 v4 = *(const u32x4*)((const char*)Sh + dd * 256 + (((sc ^ (dd & 15))) << 4));
            *(u32x4*)(dst + (size_t)dd * 2048 + s0 + sc * 8) = v4;
        }
    }
}

// ---------------- causal flash attention (round-25/27: K dbuf, write-after-drain) ----------------
__global__ __launch_bounds__(256, 2) void attn_k(const u16* __restrict__ Qb, const u16* __restrict__ Kb,
                                                 const u16* __restrict__ Vb, u16* __restrict__ Ob) {
    __shared__ char smem[65536];
    u16* Vts = (u16*)(smem + 32768);    // 16KB [128 d][64 kv], chunk^=(d&7)^((d>>3)&7)
    char* Pall = smem + 49152;          // 16KB: 8 x 2KB per (wave,frag)
    const int tid = threadIdx.x;
    const int lane = tid & 63, w = tid >> 6;
    const int g = lane >> 4, r = lane & 15;

    // balanced complementary remap (bijective over 512)
    const int lid = blockIdx.y * gridDim.x + blockIdx.x;  // 0..511
    const int cpy = lid >> 8, p = lid & 255;
    const int bh = p & 31;
    const int qblk = cpy ? (7 - (p >> 5)) : ((p >> 5) + 8);

    const int b = bh >> 4, h = bh & 15;
    const int hkv = h >> 2;
    const int q0 = qblk * 128;
    const u16* Qh = Qb + ((size_t)(b * 16 + h) << 18);
    const u16* Kh = Kb + ((size_t)(b * 4 + hkv) << 18);
    const u16* Vh = Vb + ((size_t)(b * 4 + hkv) << 18);   // Vt: [128 d][2048 s]

    s16x8 qf[2][4];
#pragma unroll
    for (int qq = 0; qq < 2; ++qq)
#pragma unroll
        for (int c = 0; c < 4; ++c)
            qf[qq][c] = *(const s16x8*)(Qh + (size_t)(q0 + qq * 64 + w * 16 + r) * 128 + c * 32 + g * 8);

    f32x4 o[2][8] = {};
    float mrun[2] = {-1e30f, -1e30f};
    float lrun[2] = {0.f, 0.f};
    const int fmax[2] = { q0 + w * 16 + 15, q0 + 64 + w * 16 + 15 };

    const int ntiles = 2 * qblk + 2;
    const int krow0 = tid >> 4, kch = tid & 15;

    u32x4 kpr[4], vpr[4];
    // ---- prologue: stage K0/V0, preload K1/V1 ----
#pragma unroll
    for (int it = 0; it < 4; ++it)
        kpr[it] = *(const u32x4*)(Kh + (size_t)(krow0 + it * 16) * 128 + kch * 8);
#pragma unroll
    for (int it = 0; it < 4; ++it) {
        int task = tid + it * 256;
        vpr[it] = *(const u32x4*)(Vh + (size_t)(task >> 3) * 2048 + (task & 7) * 8);
    }
#pragma unroll
    for (int it = 0; it < 4; ++it) {
        int row = krow0 + it * 16;
        *(u32x4*)(smem + row * 256 + ((kch ^ (row & 7)) << 4)) = kpr[it];   // buf0
    }
#pragma unroll
    for (int it = 0; it < 4; ++it) {
        int task = tid + it * 256;
        int d = task >> 3, ch = task & 7;
        *(u32x4*)((char*)Vts + d * 128 + ((ch ^ (d & 7) ^ ((d >> 3) & 7)) << 4)) = vpr[it];
    }
    if (ntiles > 1) {
#pragma unroll
        for (int it = 0; it < 4; ++it)
            kpr[it] = *(const u32x4*)(Kh + (size_t)(64 + krow0 + it * 16) * 128 + kch * 8);
#pragma unroll
        for (int it = 0; it < 4; ++it) {
            int task = tid + it * 256;
            vpr[it] = *(const u32x4*)(Vh + (size_t)(task >> 3) * 2048 + 64 + (task & 7) * 8);
        }
    }
    __syncthreads();

    for (int t = 0; t < ntiles; ++t) {
        const int kv0 = t * 64;
        const char* kb = smem + ((t & 1) << 14);
        // ---- QK^T from K[t] ----
        f32x4 st4[2][4];
#pragma unroll
        for (int ts = 0; ts < 4; ++ts) {
            int row = ts * 16 + r;
            s16x8 kf[4];
#pragma unroll
            for (int c = 0; c < 4; ++c)
                kf[c] = *(const s16x8*)(kb + row * 256 + (((c * 4 + g) ^ (row & 7)) << 4));
            f32x4 a0 = {}, a1 = {};
            if (kv0 <= fmax[0])
#pragma unroll
                for (int c = 0; c < 4; ++c) a0 = MFMA16(kf[c], qf[0][c], a0);
            if (kv0 <= fmax[1])
#pragma unroll
                for (int c = 0; c < 4; ++c) a1 = MFMA16(kf[c], qf[1][c], a1);
            st4[0][ts] = a0;
            st4[1][ts] = a1;
        }
        // ---- per-frag online softmax (defer-max THR=8) + P write ----
#pragma unroll
        for (int qq = 0; qq < 2; ++qq) {
            if (kv0 > fmax[qq]) continue;   // wave-uniform
            const int qg = q0 + qq * 64 + w * 16 + r;
            float sv[16];
            float mtile = -1e30f;
#pragma unroll
            for (int ts = 0; ts < 4; ++ts)
#pragma unroll
                for (int i = 0; i < 4; ++i) {
                    int kvg = kv0 + ts * 16 + g * 4 + i;
                    float s = st4[qq][ts][i] * 0.08838834764831845f;
                    s = (kvg > qg) ? -1e30f : s;
                    sv[ts * 4 + i] = s;
                    mtile = fmaxf(mtile, s);
                }
            mtile = fmaxf(mtile, __shfl_xor(mtile, 16));
            mtile = fmaxf(mtile, __shfl_xor(mtile, 32));
            float mold = mrun[qq];
            if (!__all(mtile <= mold + 8.0f)) {
                float mnew = fmaxf(mold, mtile);
                float corr = __expf(mold - mnew);
#pragma unroll
                for (int dsb = 0; dsb < 8; ++dsb)
#pragma unroll
                    for (int i = 0; i < 4; ++i) o[qq][dsb][i] *= corr;
                lrun[qq] *= corr;
                mrun[qq] = mnew;
            }
            float mm = mrun[qq];
            float psum = 0.f;
            unsigned int pw[8];
#pragma unroll
            for (int ts = 0; ts < 4; ++ts) {
                float p0 = __expf(sv[ts * 4 + 0] - mm);
                float p1 = __expf(sv[ts * 4 + 1] - mm);
                float p2 = __expf(sv[ts * 4 + 2] - mm);
                float p3 = __expf(sv[ts * 4 + 3] - mm);
                psum += (p0 + p1) + (p2 + p3);
                pw[ts * 2 + 0] = (unsigned int)f2bf(p0) | ((unsigned int)f2bf(p1) << 16);
                pw[ts * 2 + 1] = (unsigned int)f2bf(p2) | ((unsigned int)f2bf(p3) << 16);
            }
            psum += __shfl_xor(psum, 16);
            psum += __shfl_xor(psum, 32);
            lrun[qq] += psum;
            char* pbase = Pall + (w * 2 + qq) * 2048;
#pragma unroll
            for (int ts = 0; ts < 4; ++ts) {
                int chunk = (ts * 2 + (g >> 1)) ^ (r & 7);
                u32x2 val = { pw[ts * 2], pw[ts * 2 + 1] };
                *(u32x2*)(pbase + r * 128 + chunk * 16 + (g & 1) * 8) = val;
            }
        }
        asm volatile("s_waitcnt lgkmcnt(0)" ::: "memory");
        // ---- write K[t+1] to inactive buffer AFTER the drain (overlaps PV); issue K[t+2] ----
        if (t + 1 < ntiles) {
            char* kbn = smem + (((t + 1) & 1) << 14);
#pragma unroll
            for (int it = 0; it < 4; ++it) {
                int row = krow0 + it * 16;
                *(u32x4*)(kbn + row * 256 + ((kch ^ (row & 7)) << 4)) = kpr[it];
            }
            if (t + 2 < ntiles) {
                const int kn2 = kv0 + 128;
#pragma unroll
                for (int it = 0; it < 4; ++it)
                    kpr[it] = *(const u32x4*)(Kh + (size_t)(kn2 + krow0 + it * 16) * 128 + kch * 8);
            }
        }
        // ---- PV from Vts ----
#pragma unroll
        for (int c = 0; c < 2; ++c) {
            s16x8 vf[8];
#pragma unroll
            for (int dsb = 0; dsb < 8; ++dsb) {
                int d = dsb * 16 + r;
                vf[dsb] = *(const s16x8*)((const char*)Vts + d * 128 +
                    ((((c * 4 + g) ^ (d & 7) ^ ((d >> 3) & 7))) << 4));
            }
#pragma unroll
            for (int qq = 0; qq < 2; ++qq) {
                if (kv0 > fmax[qq]) continue;
                s16x8 pf = *(const s16x8*)(Pall + (w * 2 + qq) * 2048 + r * 128 +
                                           (((c * 4 + g) ^ (r & 7)) << 4));
#pragma unroll
                for (int dsb = 0; dsb < 8; ++dsb)
                    o[qq][dsb] = MFMA16(vf[dsb], pf, o[qq][dsb]);
            }
        }
        __syncthreads();                    // all waves done with V[t]; K[t+1] writes flushed
        // ---- write V[t+1]; issue V[t+2] ----
        if (t + 1 < ntiles) {
#pragma unroll
            for (int it = 0; it < 4; ++it) {
                int task = tid + it * 256;
                int d = task >> 3, ch = task & 7;
                *(u32x4*)((char*)Vts + d * 128 + ((ch ^ (d & 7) ^ ((d >> 3) & 7)) << 4)) = vpr[it];
            }
            if (t + 2 < ntiles) {
                const int kn2 = kv0 + 128;
#pragma unroll
                for (int it = 0; it < 4; ++it) {
                    int task = tid + it * 256;
                    vpr[it] = *(const u32x4*)(Vh + (size_t)(task >> 3) * 2048 + kn2 + (task & 7) * 8);
                }
            }
        }
        __syncthreads();                    // V[t+1] (and K[t+1]) visible for next step
    }
    // ---- epilogue: normalize, per-(wave,frag) LDS transpose, coalesced store ----
#pragma unroll
    for (int qq = 0; qq < 2; ++qq) {
        float linv = 1.0f / lrun[qq];
        char* obase = smem + (w << 13) + (qq << 12);   // 4KB: [16 q][128 d] bf16 (K bufs dead)
#pragma unroll
        for (int dsb = 0; dsb < 8; ++dsb)
#pragma unroll
            for (int i = 0; i < 4; ++i) {
                int d = dsb * 16 + g * 4 + i;
                *(u16*)(obase + r * 256 + d * 2) = f2bf(o[qq][dsb][i] * linv);
            }
    }
    asm volatile("s_waitcnt lgkmcnt(0)" ::: "memory");
    const int rr = lane >> 2, cbo = (lane & 3) * 32;
#pragma unroll
    for (int qq = 0; qq < 2; ++qq) {
        char* obase = smem + (w << 13) + (qq << 12);
        size_t oidx = ((size_t)b * 2048 + q0 + qq * 64 + w * 16 + rr) * 2048 + h * 128 + cbo;
#pragma unroll
        for (int p2 = 0; p2 < 4; ++p2) {
            u32x4 vv = *(const u32x4*)(obase + rr * 256 + cbo * 2 + p2 * 16);
            *(u32x4*)(Ob + oidx + p2 * 8) = vv;
        }
    }
}

extern "C" void kernel_launch(void* const* d_in, const int* in_sizes, int n_in,
                              void* d_out, int out_size, void* d_ws, size_t ws_size,
                              hipStream_t stream) {
    const float* hidden = (const float*)d_in[0];
    const int* pos = (const int*)d_in[1];
    const float* wq = (const float*)d_in[2];
    const float* wk = (const float*)d_in[3];
    const float* wv = (const float*)d_in[4];
    const float* wo = (const float*)d_in[5];
    float* out = (float*)d_out;

    char* ws = (char*)d_ws;
    size_t off = 0;
    auto alloc = [&](size_t bytes) { char* p = ws + off; off += (bytes + 255) & ~255ULL; return p; };
    u16* Xb   = (u16*)alloc(8388608ULL * 2);     // hidden bf16 [4096][2048]
    u16* WB   = (u16*)alloc(6291456ULL * 2);     // [wq;wk;wv] bf16 [3072][2048]
    u16* WoB  = (u16*)alloc(4194304ULL * 2);     // wo bf16 [2048][2048]
    u16* Qb   = (u16*)alloc(8388608ULL * 2);     // [B*16][2048][128]
    u16* Kb   = (u16*)alloc(2097152ULL * 2);     // [B*4][2048][128]
    u16* Vb   = (u16*)alloc(2097152ULL * 2);     // [B*4][128][2048] (transposed)
    u16* Ab   = (u16*)alloc(8388608ULL * 2);     // attn out bf16 [4096][2048]
    float* ctab = (float*)alloc(262144ULL * 4);
    float* stab = (float*)alloc(262144ULL * 4);

    cast_all<<<19456, 256, 0, stream>>>(hidden, wq, wk, wv, wo, pos, Xb, WB, WoB, ctab, stab);
    gemm_bt<1><<<dim3(24, 32), 256, 0, stream>>>(Xb, WB, nullptr, 4096, 3072, 2048,
                                                 ctab, stab, Qb, Kb, Vb);
    attn_k<<<dim3(16, 32), 256, 0, stream>>>(Qb, Kb, Vb, Ab);
    gemm_bt<0><<<dim3(16, 32), 256, 0, stream>>>(Ab, WoB, out, 4096, 2048, 2048,
                                                 nullptr, nullptr, nullptr, nullptr, nullptr);
}

// Round 32
// 228.458 us; speedup vs baseline: 1.0042x; 1.0013x over previous
//
#include <hip/hip_runtime.h>
#include <hip/hip_bf16.h>
#include <cstdint>

typedef unsigned short u16;
typedef __attribute__((ext_vector_type(4))) float f32x4;
typedef __attribute__((ext_vector_type(8))) short s16x8;
typedef __attribute__((ext_vector_type(4))) unsigned int u32x4;
typedef __attribute__((ext_vector_type(2))) unsigned int u32x2;
typedef __attribute__((ext_vector_type(4))) unsigned short u16x4;
typedef __attribute__((ext_vector_type(8))) unsigned short u16x8;

#define MFMA16(a, b, c) __builtin_amdgcn_mfma_f32_16x16x32_bf16(a, b, c, 0, 0, 0)
#define GLOAD16(g, l) __builtin_amdgcn_global_load_lds((const __attribute__((address_space(1))) void*)(g), (__attribute__((address_space(3))) void*)(l), 16, 0, 0)

__device__ __forceinline__ u16 f2bf(float f) {
    union { float f; uint32_t u; } v{f};
    uint32_t r = v.u + 0x7FFF + ((v.u >> 16) & 1);
    return (u16)(r >> 16);
}
__device__ __forceinline__ float bf2f(u16 b) {
    union { uint32_t u; float f; } v;
    v.u = ((uint32_t)b) << 16;
    return v.f;
}

// ---------------- fused cast (all 5 inputs) + RoPE table, 1 launch ----------------
__global__ void cast_all(const float* __restrict__ h, const float* __restrict__ wq,
                         const float* __restrict__ wk, const float* __restrict__ wv,
                         const float* __restrict__ wo, const int* __restrict__ pos,
                         u16* __restrict__ Xb, u16* __restrict__ WB, u16* __restrict__ WoB,
                         float* __restrict__ ct, float* __restrict__ st) {
    if (blockIdx.x >= 18432) {
        int i = (blockIdx.x - 18432) * 256 + threadIdx.x;   // 1024*256 = 262144
        int j = i & 63;
        int bs = i >> 6;
        float p = (float)pos[bs];
        float invf = powf(10000.0f, -(float)j * (1.0f / 64.0f));
        float ang = p * invf;
        ct[i] = cosf(ang);
        st[i] = sinf(ang);
        return;
    }
    int i = blockIdx.x * 256 + threadIdx.x;   // 18432*256 = 4718592 exactly
    const float* src; u16* dst; int off;
    if (i < 2097152)      { src = h;  dst = Xb;           off = i; }
    else if (i < 3145728) { src = wq; dst = WB;           off = i - 2097152; }
    else if (i < 3407872) { src = wk; dst = WB + 4194304; off = i - 3145728; }
    else if (i < 3670016) { src = wv; dst = WB + 5242880; off = i - 3407872; }
    else                  { src = wo; dst = WoB;          off = i - 3670016; }
    float4 f = ((const float4*)src)[off];
    u16x4 o = { f2bf(f.x), f2bf(f.y), f2bf(f.z), f2bf(f.w) };
    ((u16x4*)dst)[off] = o;
}

// ---------------- GEMM C = A @ B^T, 2-phase double-buffered + XCD swizzle ----------------
// FUSE=0: plain f32 C store (O-proj). FUSE=1: QKV path — RoPE+scatter epilogue
// (all 256 threads: 2 threads/token-row, 4 chunk-pairs each); V stored transposed.
template <int FUSE>
__global__ __launch_bounds__(256) void gemm_bt(const u16* __restrict__ A, const u16* __restrict__ Bw,
                                               float* __restrict__ C, int M, int N, int K,
                                               const float* __restrict__ ct, const float* __restrict__ st,
                                               u16* __restrict__ Qb, u16* __restrict__ Kb,
                                               u16* __restrict__ Vb) {
    __shared__ u16 Sh[32768];                // 64KB: buf bi at Sh + bi*16384 {A:0-8K, B:8K-16K}
    const int tid = threadIdx.x;
    const int lane = tid & 63, wid = tid >> 6;
    const int g = lane >> 4, r = lane & 15;

    const int gx = gridDim.x, nwg = gx * gridDim.y;
    int lid = blockIdx.y * gx + blockIdx.x;
    int swz = (lid % 8) * (nwg / 8) + lid / 8;
    const int bxi = swz % gx, byi = swz / gx;

    const size_t bm = (size_t)byi * 128, bn = (size_t)bxi * 128;
    const int wr = (wid >> 1) * 64, wc = (wid & 1) * 64;

    const int srow = wid * 32 + (lane >> 3);
    const int schunk = (lane & 7) ^ ((lane >> 3) & 7);
    const u16* aSrc = A + (bm + srow) * (size_t)K + schunk * 8;
    const u16* bSrc = Bw + (bn + srow) * (size_t)K + schunk * 8;

    auto STAGE = [&](int ktEl, int bi) {
        u16* aD = Sh + bi * 16384 + wid * 2048;
        u16* bD = Sh + bi * 16384 + 8192 + wid * 2048;
#pragma unroll
        for (int j = 0; j < 4; ++j) {
            GLOAD16(aSrc + (size_t)(j * 8) * K + ktEl, aD + j * 512);
            GLOAD16(bSrc + (size_t)(j * 8) * K + ktEl, bD + j * 512);
        }
    };

    f32x4 acc[4][4] = {};
    const int nk = K >> 6;
    STAGE(0, 0);
    __syncthreads();
    for (int t = 0; t < nk; ++t) {
        if (t + 1 < nk) STAGE((t + 1) << 6, (t + 1) & 1);
        const u16* As = Sh + (t & 1) * 16384;
        const u16* Bs = As + 8192;
        s16x8 af[4][2], bfr[4][2];
#pragma unroll
        for (int m = 0; m < 4; ++m)
#pragma unroll
            for (int kk = 0; kk < 2; ++kk) {
                int rowa = wr + m * 16 + r;
                af[m][kk] = *(const s16x8*)(As + rowa * 64 + (((kk * 4 + g) ^ (rowa & 7)) << 3));
                int rowb = wc + m * 16 + r;
                bfr[m][kk] = *(const s16x8*)(Bs + rowb * 64 + (((kk * 4 + g) ^ (rowb & 7)) << 3));
            }
#pragma unroll
        for (int m = 0; m < 4; ++m)
#pragma unroll
            for (int n = 0; n < 4; ++n) {
                acc[m][n] = MFMA16(af[m][0], bfr[n][0], acc[m][n]);
                acc[m][n] = MFMA16(af[m][1], bfr[n][1], acc[m][n]);
            }
        __syncthreads();
    }
    if (FUSE == 0) {
#pragma unroll
        for (int m = 0; m < 4; ++m)
#pragma unroll
            for (int n = 0; n < 4; ++n)
#pragma unroll
                for (int i = 0; i < 4; ++i) {
                    size_t row = bm + wr + m * 16 + g * 4 + i;
                    size_t col = bn + wc + n * 16 + r;
                    C[row * N + col] = acc[m][n][i];
                }
        return;
    }
    const int hb = bxi;
    if (hb < 20) {
#pragma unroll
        for (int m = 0; m < 4; ++m)
#pragma unroll
            for (int n = 0; n < 4; ++n)
#pragma unroll
                for (int i = 0; i < 4; ++i) {
                    int rowl = wr + m * 16 + g * 4 + i;
                    int col = wc + n * 16 + r;
                    int c4 = col >> 3;
                    *(u16*)((char*)Sh + rowl * 256 + (((c4 ^ (rowl & 15))) << 4) + ((col & 7) << 1)) =
                        f2bf(acc[m][n][i]);
                }
        __syncthreads();
        {
            // all 256 threads: 2 threads per token-row, 4 chunk-pairs each
            const int rowl = tid >> 1;
            const int c4b = (tid & 1) * 4;
            const size_t tok = bm + rowl;
            const int b = (int)(tok >> 11), s = (int)(tok & 2047);
            u16* dst;
            if (hb < 16) dst = Qb + (((size_t)(b * 16 + hb) * 2048 + s) << 7);
            else         dst = Kb + (((size_t)(b * 4 + (hb - 16)) * 2048 + s) << 7);
            const char* tb = (const char*)Sh + rowl * 256;
            const float* ctr = ct + tok * 64;
            const float* str = st + tok * 64;
#pragma unroll
            for (int c4i = 0; c4i < 4; ++c4i) {
                int c4 = c4b + c4i;
                u32x4 lo4 = *(const u32x4*)(tb + ((c4 ^ (rowl & 15)) << 4));
                u32x4 hi4 = *(const u32x4*)(tb + (((c4 + 8) ^ (rowl & 15)) << 4));
                const u16* lo = (const u16*)&lo4;
                const u16* hi = (const u16*)&hi4;
                u16x4 o0, o1, o2, o3;
                u16* olo[2] = { (u16*)&o0, (u16*)&o1 };
                u16* ohi[2] = { (u16*)&o2, (u16*)&o3 };
#pragma unroll
                for (int j = 0; j < 8; ++j) {
                    float c = ctr[c4 * 8 + j], sn = str[c4 * 8 + j];
                    float xl = bf2f(lo[j]), xh = bf2f(hi[j]);
                    olo[j >> 2][j & 3] = f2bf(xl * c - xh * sn);
                    ohi[j >> 2][j & 3] = f2bf(xh * c + xl * sn);
                }
                *(u16x4*)(dst + c4 * 8) = o0;
                *(u16x4*)(dst + c4 * 8 + 4) = o1;
                *(u16x4*)(dst + 64 + c4 * 8) = o2;
                *(u16x4*)(dst + 64 + c4 * 8 + 4) = o3;
            }
        }
    } else {
#pragma unroll
        for (int m = 0; m < 4; ++m) {
            int tokb = wr + m * 16 + g * 4;
            int chunk = tokb >> 3;
            int sub = (g & 1) * 8;
#pragma unroll
            for (int n = 0; n < 4; ++n) {
                int d = wc + n * 16 + r;
                u16x4 v = { f2bf(acc[m][n][0]), f2bf(acc[m][n][1]),
                            f2bf(acc[m][n][2]), f2bf(acc[m][n][3]) };
                *(u16x4*)((char*)Sh + d * 256 + (((chunk ^ (d & 15))) << 4) + sub) = v;
            }
        }
        __syncthreads();
        const int b = (int)(bm >> 11), s0 = (int)(bm & 2047);
        u16* dst = Vb + (size_t)(b * 4 + (hb - 20)) * 262144;
        const int dd = tid >> 1, half = (tid & 1) * 8;
#pragma unroll
        for (int c8 = 0; c8 < 8; ++c8) {
            int sc = half + c8;
            u32x4 v4 = *(const u32x4*)((const char*)Sh + dd * 256 + (((sc ^ (dd & 15))) << 4));
            *(u32x4*)(dst + (size_t)dd * 2048 + s0 + sc * 8) = v4;
        }
    }
}

// ---------------- causal flash attention (round-25/27: K dbuf, write-after-drain) ----------------
__global__ __launch_bounds__(256, 2) void attn_k(const u16* __restrict__ Qb, const u16* __restrict__ Kb,
                                                 const u16* __restrict__ Vb, u16* __restrict__ Ob) {
    __shared__ char smem[65536];
    u16* Vts = (u16*)(smem + 32768);    // 16KB [128 d][64 kv], chunk^=(d&7)^((d>>3)&7)
    char* Pall = smem + 49152;          // 16KB: 8 x 2KB per (wave,frag)
    const int tid = threadIdx.x;
    const int lane = tid & 63, w = tid >> 6;
    const int g = lane >> 4, r = lane & 15;

    // balanced complementary remap (bijective over 512)
    const int lid = blockIdx.y * gridDim.x + blockIdx.x;  // 0..511
    const int cpy = lid >> 8, p = lid & 255;
    const int bh = p & 31;
    const int qblk = cpy ? (7 - (p >> 5)) : ((p >> 5) + 8);

    const int b = bh >> 4, h = bh & 15;
    const int hkv = h >> 2;
    const int q0 = qblk * 128;
    const u16* Qh = Qb + ((size_t)(b * 16 + h) << 18);
    const u16* Kh = Kb + ((size_t)(b * 4 + hkv) << 18);
    const u16* Vh = Vb + ((size_t)(b * 4 + hkv) << 18);   // Vt: [128 d][2048 s]

    s16x8 qf[2][4];
#pragma unroll
    for (int qq = 0; qq < 2; ++qq)
#pragma unroll
        for (int c = 0; c < 4; ++c)
            qf[qq][c] = *(const s16x8*)(Qh + (size_t)(q0 + qq * 64 + w * 16 + r) * 128 + c * 32 + g * 8);

    f32x4 o[2][8] = {};
    float mrun[2] = {-1e30f, -1e30f};
    float lrun[2] = {0.f, 0.f};
    const int fmax[2] = { q0 + w * 16 + 15, q0 + 64 + w * 16 + 15 };

    const int ntiles = 2 * qblk + 2;
    const int krow0 = tid >> 4, kch = tid & 15;

    u32x4 kpr[4], vpr[4];
    // ---- prologue: stage K0/V0, preload K1/V1 ----
#pragma unroll
    for (int it = 0; it < 4; ++it)
        kpr[it] = *(const u32x4*)(Kh + (size_t)(krow0 + it * 16) * 128 + kch * 8);
#pragma unroll
    for (int it = 0; it < 4; ++it) {
        int task = tid + it * 256;
        vpr[it] = *(const u32x4*)(Vh + (size_t)(task >> 3) * 2048 + (task & 7) * 8);
    }
#pragma unroll
    for (int it = 0; it < 4; ++it) {
        int row = krow0 + it * 16;
        *(u32x4*)(smem + row * 256 + ((kch ^ (row & 7)) << 4)) = kpr[it];   // buf0
    }
#pragma unroll
    for (int it = 0; it < 4; ++it) {
        int task = tid + it * 256;
        int d = task >> 3, ch = task & 7;
        *(u32x4*)((char*)Vts + d * 128 + ((ch ^ (d & 7) ^ ((d >> 3) & 7)) << 4)) = vpr[it];
    }
    if (ntiles > 1) {
#pragma unroll
        for (int it = 0; it < 4; ++it)
            kpr[it] = *(const u32x4*)(Kh + (size_t)(64 + krow0 + it * 16) * 128 + kch * 8);
#pragma unroll
        for (int it = 0; it < 4; ++it) {
            int task = tid + it * 256;
            vpr[it] = *(const u32x4*)(Vh + (size_t)(task >> 3) * 2048 + 64 + (task & 7) * 8);
        }
    }
    __syncthreads();

    for (int t = 0; t < ntiles; ++t) {
        const int kv0 = t * 64;
        const char* kb = smem + ((t & 1) << 14);
        // ---- QK^T from K[t] ----
        f32x4 st4[2][4];
#pragma unroll
        for (int ts = 0; ts < 4; ++ts) {
            int row = ts * 16 + r;
            s16x8 kf[4];
#pragma unroll
            for (int c = 0; c < 4; ++c)
                kf[c] = *(const s16x8*)(kb + row * 256 + (((c * 4 + g) ^ (row & 7)) << 4));
            f32x4 a0 = {}, a1 = {};
            if (kv0 <= fmax[0])
#pragma unroll
                for (int c = 0; c < 4; ++c) a0 = MFMA16(kf[c], qf[0][c], a0);
            if (kv0 <= fmax[1])
#pragma unroll
                for (int c = 0; c < 4; ++c) a1 = MFMA16(kf[c], qf[1][c], a1);
            st4[0][ts] = a0;
            st4[1][ts] = a1;
        }
        // ---- per-frag online softmax (defer-max THR=8) + P write ----
#pragma unroll
        for (int qq = 0; qq < 2; ++qq) {
            if (kv0 > fmax[qq]) continue;   // wave-uniform
            const int qg = q0 + qq * 64 + w * 16 + r;
            float sv[16];
            float mtile = -1e30f;
#pragma unroll
            for (int ts = 0; ts < 4; ++ts)
#pragma unroll
                for (int i = 0; i < 4; ++i) {
                    int kvg = kv0 + ts * 16 + g * 4 + i;
                    float s = st4[qq][ts][i] * 0.08838834764831845f;
                    s = (kvg > qg) ? -1e30f : s;
                    sv[ts * 4 + i] = s;
                    mtile = fmaxf(mtile, s);
                }
            mtile = fmaxf(mtile, __shfl_xor(mtile, 16));
            mtile = fmaxf(mtile, __shfl_xor(mtile, 32));
            float mold = mrun[qq];
            if (!__all(mtile <= mold + 8.0f)) {
                float mnew = fmaxf(mold, mtile);
                float corr = __expf(mold - mnew);
#pragma unroll
                for (int dsb = 0; dsb < 8; ++dsb)
#pragma unroll
                    for (int i = 0; i < 4; ++i) o[qq][dsb][i] *= corr;
                lrun[qq] *= corr;
                mrun[qq] = mnew;
            }
            float mm = mrun[qq];
            float psum = 0.f;
            unsigned int pw[8];
#pragma unroll
            for (int ts = 0; ts < 4; ++ts) {
                float p0 = __expf(sv[ts * 4 + 0] - mm);
                float p1 = __expf(sv[ts * 4 + 1] - mm);
                float p2 = __expf(sv[ts * 4 + 2] - mm);
                float p3 = __expf(sv[ts * 4 + 3] - mm);
                psum += (p0 + p1) + (p2 + p3);
                pw[ts * 2 + 0] = (unsigned int)f2bf(p0) | ((unsigned int)f2bf(p1) << 16);
                pw[ts * 2 + 1] = (unsigned int)f2bf(p2) | ((unsigned int)f2bf(p3) << 16);
            }
            psum += __shfl_xor(psum, 16);
            psum += __shfl_xor(psum, 32);
            lrun[qq] += psum;
            char* pbase = Pall + (w * 2 + qq) * 2048;
#pragma unroll
            for (int ts = 0; ts < 4; ++ts) {
                int chunk = (ts * 2 + (g >> 1)) ^ (r & 7);
                u32x2 val = { pw[ts * 2], pw[ts * 2 + 1] };
                *(u32x2*)(pbase + r * 128 + chunk * 16 + (g & 1) * 8) = val;
            }
        }
        asm volatile("s_waitcnt lgkmcnt(0)" ::: "memory");
        // ---- write K[t+1] to inactive buffer AFTER the drain (overlaps PV); issue K[t+2] ----
        if (t + 1 < ntiles) {
            char* kbn = smem + (((t + 1) & 1) << 14);
#pragma unroll
            for (int it = 0; it < 4; ++it) {
                int row = krow0 + it * 16;
                *(u32x4*)(kbn + row * 256 + ((kch ^ (row & 7)) << 4)) = kpr[it];
            }
            if (t + 2 < ntiles) {
                const int kn2 = kv0 + 128;
#pragma unroll
                for (int it = 0; it < 4; ++it)
                    kpr[it] = *(const u32x4*)(Kh + (size_t)(kn2 + krow0 + it * 16) * 128 + kch * 8);
            }
        }
        // ---- PV from Vts ----
#pragma unroll
        for (int c = 0; c < 2; ++c) {
            s16x8 vf[8];
#pragma unroll
            for (int dsb = 0; dsb < 8; ++dsb) {
                int d = dsb * 16 + r;
                vf[dsb] = *(const s16x8*)((const char*)Vts + d * 128 +
                    ((((c * 4 + g) ^ (d & 7) ^ ((d >> 3) & 7))) << 4));
            }
#pragma unroll
            for (int qq = 0; qq < 2; ++qq) {
                if (kv0 > fmax[qq]) continue;
                s16x8 pf = *(const s16x8*)(Pall + (w * 2 + qq) * 2048 + r * 128 +
                                           (((c * 4 + g) ^ (r & 7)) << 4));
#pragma unroll
                for (int dsb = 0; dsb < 8; ++dsb)
                    o[qq][dsb] = MFMA16(vf[dsb], pf, o[qq][dsb]);
            }
        }
        __syncthreads();                    // all waves done with V[t]; K[t+1] writes flushed
        // ---- write V[t+1]; issue V[t+2] ----
        if (t + 1 < ntiles) {
#pragma unroll
            for (int it = 0; it < 4; ++it) {
                int task = tid + it * 256;
                int d = task >> 3, ch = task & 7;
                *(u32x4*)((char*)Vts + d * 128 + ((ch ^ (d & 7) ^ ((d >> 3) & 7)) << 4)) = vpr[it];
            }
            if (t + 2 < ntiles) {
                const int kn2 = kv0 + 128;
#pragma unroll
                for (int it = 0; it < 4; ++it) {
                    int task = tid + it * 256;
                    vpr[it] = *(const u32x4*)(Vh + (size_t)(task >> 3) * 2048 + kn2 + (task & 7) * 8);
                }
            }
        }
        __syncthreads();                    // V[t+1] (and K[t+1]) visible for next step
    }
    // ---- epilogue: normalize, per-(wave,frag) LDS transpose, coalesced store ----
#pragma unroll
    for (int qq = 0; qq < 2; ++qq) {
        float linv = 1.0f / lrun[qq];
        char* obase = smem + (w << 13) + (qq << 12);   // 4KB: [16 q][128 d] bf16 (K bufs dead)
#pragma unroll
        for (int dsb = 0; dsb < 8; ++dsb)
#pragma unroll
            for (int i = 0; i < 4; ++i) {
                int d = dsb * 16 + g * 4 + i;
                *(u16*)(obase + r * 256 + d * 2) = f2bf(o[qq][dsb][i] * linv);
            }
    }
    asm volatile("s_waitcnt lgkmcnt(0)" ::: "memory");
    const int rr = lane >> 2, cbo = (lane & 3) * 32;
#pragma unroll
    for (int qq = 0; qq < 2; ++qq) {
        char* obase = smem + (w << 13) + (qq << 12);
        size_t oidx = ((size_t)b * 2048 + q0 + qq * 64 + w * 16 + rr) * 2048 + h * 128 + cbo;
#pragma unroll
        for (int p2 = 0; p2 < 4; ++p2) {
            u32x4 vv = *(const u32x4*)(obase + rr * 256 + cbo * 2 + p2 * 16);
            *(u32x4*)(Ob + oidx + p2 * 8) = vv;
        }
    }
}

extern "C" void kernel_launch(void* const* d_in, const int* in_sizes, int n_in,
                              void* d_out, int out_size, void* d_ws, size_t ws_size,
                              hipStream_t stream) {
    const float* hidden = (const float*)d_in[0];
    const int* pos = (const int*)d_in[1];
    const float* wq = (const float*)d_in[2];
    const float* wk = (const float*)d_in[3];
    const float* wv = (const float*)d_in[4];
    const float* wo = (const float*)d_in[5];
    float* out = (float*)d_out;

    char* ws = (char*)d_ws;
    size_t off = 0;
    auto alloc = [&](size_t bytes) { char* p = ws + off; off += (bytes + 255) & ~255ULL; return p; };
    u16* Xb   = (u16*)alloc(8388608ULL * 2);     // hidden bf16 [4096][2048]
    u16* WB   = (u16*)alloc(6291456ULL * 2);     // [wq;wk;wv] bf16 [3072][2048]
    u16* WoB  = (u16*)alloc(4194304ULL * 2);     // wo bf16 [2048][2048]
    u16* Qb   = (u16*)alloc(8388608ULL * 2);     // [B*16][2048][128]
    u16* Kb   = (u16*)alloc(2097152ULL * 2);     // [B*4][2048][128]
    u16* Vb   = (u16*)alloc(2097152ULL * 2);     // [B*4][128][2048] (transposed)
    u16* Ab   = (u16*)alloc(8388608ULL * 2);     // attn out bf16 [4096][2048]
    float* ctab = (float*)alloc(262144ULL * 4);
    float* stab = (float*)alloc(262144ULL * 4);

    cast_all<<<19456, 256, 0, stream>>>(hidden, wq, wk, wv, wo, pos, Xb, WB, WoB, ctab, stab);
    gemm_bt<1><<<dim3(24, 32), 256, 0, stream>>>(Xb, WB, nullptr, 4096, 3072, 2048,
                                                 ctab, stab, Qb, Kb, Vb);
    attn_k<<<dim3(16, 32), 256, 0, stream>>>(Qb, Kb, Vb, Ab);
    gemm_bt<0><<<dim3(16, 32), 256, 0, stream>>>(Ab, WoB, out, 4096, 2048, 2048,
                                                 nullptr, nullptr, nullptr, nullptr, nullptr);
}